// Round 3
// baseline (172.269 us; speedup 1.0000x reference)
//
#include <hip/hip_runtime.h>
#include <math.h>

#define LN_EPS 1e-5f

// Problem: B=8 scenes, A=16 agents, L=80 lanes, D=128, H=6.
// N=768 nodes (128 agents first), 96 nodes/scene, dense per-scene attention.
// ws layout (floats): KV[768][1536] | Qb[128][768] | AO[128][768]

// ---------------------------------------------------------------------------
// Kernel 1: KV = nodes @ [Wk | Wv(relu)] , Qb = agents @ Wq
// 64 rows x 64 cols per block, 256 threads, 4x4 per thread. 312 blocks.
__global__ __launch_bounds__(256) void k_qkv(
    const float* __restrict__ agents, const float* __restrict__ lanes,
    const float* __restrict__ Wq, const float* __restrict__ Wk,
    const float* __restrict__ Wv, float* __restrict__ KV, float* __restrict__ Qb)
{
    __shared__ float Ast[128][64];   // [k][row] 32 KB
    __shared__ float Bst[32][64];    // [k][col] 8 KB

    const int tid = threadIdx.x;
    const int bid = blockIdx.x;

    const float* W;
    float* Out;
    int r0, wc0, dc0, dstride;
    bool dorelu = false;
    if (bid < 288) {                       // KV: 12 row-blocks x 24 col-blocks
        const int br = bid % 12, bc = bid / 12;
        r0 = br * 64;
        if (bc < 12) { W = Wk; wc0 = bc * 64; dc0 = wc0; }
        else         { W = Wv; wc0 = (bc - 12) * 64; dc0 = 768 + wc0; dorelu = true; }
        Out = KV; dstride = 1536;
    } else {                               // Q: 2 row-blocks x 12 col-blocks
        const int idx = bid - 288;
        r0 = (idx & 1) * 64;
        W = Wq; wc0 = (idx >> 1) * 64; dc0 = wc0;
        Out = Qb; dstride = 768;
    }

    // stage A tile (64 rows x 128 k), transposed into Ast[k][row]
    {
        const int row = tid >> 2;      // 0..63
        const int kv = tid & 3;        // 0..3
        const int gr = r0 + row;
        const float* src = (gr < 128) ? (agents + gr * 128)
                                      : (lanes + (size_t)(gr - 128) * 128);
        #pragma unroll
        for (int j = 0; j < 8; ++j) {
            const int k0 = kv * 4 + j * 16;
            const float4 a = *(const float4*)(src + k0);
            Ast[k0 + 0][row] = a.x; Ast[k0 + 1][row] = a.y;
            Ast[k0 + 2][row] = a.z; Ast[k0 + 3][row] = a.w;
        }
    }

    // prefetch B chunk 0: 32 k-rows x 64 cols
    const int pk = tid >> 4;    // 0..15 (k rows pk, pk+16)
    const int pc = tid & 15;    // f4 col
    const float* wbase = W + wc0 + pc * 4;
    float4 pre0 = *(const float4*)(wbase + (size_t)pk * 768);
    float4 pre1 = *(const float4*)(wbase + (size_t)(pk + 16) * 768);

    __syncthreads();

    const int tx = tid & 15;    // f4 col
    const int ty = tid >> 4;    // rows 4ty..4ty+3
    float acc[4][4] = {};

    for (int kc = 0; kc < 4; ++kc) {
        *(float4*)&Bst[pk][pc * 4]      = pre0;
        *(float4*)&Bst[pk + 16][pc * 4] = pre1;
        __syncthreads();
        if (kc < 3) {
            const float* wn = wbase + (size_t)(kc + 1) * 32 * 768;
            pre0 = *(const float4*)(wn + (size_t)pk * 768);
            pre1 = *(const float4*)(wn + (size_t)(pk + 16) * 768);
        }
        #pragma unroll 8
        for (int kk = 0; kk < 32; ++kk) {
            const float4 a = *(const float4*)&Ast[kc * 32 + kk][ty * 4];
            const float4 b = *(const float4*)&Bst[kk][tx * 4];
            const float av[4] = {a.x, a.y, a.z, a.w};
            #pragma unroll
            for (int i = 0; i < 4; ++i) {
                acc[i][0] += av[i] * b.x; acc[i][1] += av[i] * b.y;
                acc[i][2] += av[i] * b.z; acc[i][3] += av[i] * b.w;
            }
        }
        __syncthreads();
    }

    #pragma unroll
    for (int i = 0; i < 4; ++i) {
        const int rr = r0 + ty * 4 + i;
        float4 v;
        v.x = dorelu ? fmaxf(acc[i][0], 0.f) : acc[i][0];
        v.y = dorelu ? fmaxf(acc[i][1], 0.f) : acc[i][1];
        v.z = dorelu ? fmaxf(acc[i][2], 0.f) : acc[i][2];
        v.w = dorelu ? fmaxf(acc[i][3], 0.f) : acc[i][3];
        *(float4*)(Out + (size_t)rr * dstride + dc0 + tx * 4) = v;
    }
}

// ---------------------------------------------------------------------------
// Kernel 2: per (scene, head) attention. 48 blocks x 256 threads. (R2, verified)
__global__ __launch_bounds__(256) void k_attn(
    const float* __restrict__ KV, const float* __restrict__ Qb, float* __restrict__ AO)
{
    __shared__ float Qs[16][132];
    __shared__ float Buf[96][132];   // K, then reused for V
    __shared__ float Sm[16][100];

    const int tid = threadIdx.x;
    const int s = blockIdx.x / 6;
    const int h = blockIdx.x % 6;

    for (int idx = tid; idx < 16 * 32; idx += 256) {
        const int i = idx >> 5, dv = idx & 31;
        *(float4*)&Qs[i][dv * 4] =
            *(const float4*)(Qb + (size_t)(s * 16 + i) * 768 + h * 128 + dv * 4);
    }
    for (int idx = tid; idx < 96 * 32; idx += 256) {
        const int n = idx >> 5, dv = idx & 31;
        const int g = (n < 16) ? (s * 16 + n) : (128 + s * 80 + (n - 16));
        *(float4*)&Buf[n][dv * 4] =
            *(const float4*)(KV + (size_t)g * 1536 + h * 128 + dv * 4);
    }
    __syncthreads();

    {
        const int i0 = (tid >> 5) * 2, jc = tid & 31;
        float s00 = 0, s01 = 0, s02 = 0, s10 = 0, s11 = 0, s12 = 0;
        #pragma unroll 4
        for (int kk = 0; kk < 32; ++kk) {
            const float4 q0 = *(const float4*)&Qs[i0][kk * 4];
            const float4 q1 = *(const float4*)&Qs[i0 + 1][kk * 4];
            const float4 b0 = *(const float4*)&Buf[jc][kk * 4];
            const float4 b1 = *(const float4*)&Buf[jc + 32][kk * 4];
            const float4 b2 = *(const float4*)&Buf[jc + 64][kk * 4];
            s00 += q0.x*b0.x + q0.y*b0.y + q0.z*b0.z + q0.w*b0.w;
            s01 += q0.x*b1.x + q0.y*b1.y + q0.z*b1.z + q0.w*b1.w;
            s02 += q0.x*b2.x + q0.y*b2.y + q0.z*b2.z + q0.w*b2.w;
            s10 += q1.x*b0.x + q1.y*b0.y + q1.z*b0.z + q1.w*b0.w;
            s11 += q1.x*b1.x + q1.y*b1.y + q1.z*b1.z + q1.w*b1.w;
            s12 += q1.x*b2.x + q1.y*b2.y + q1.z*b2.z + q1.w*b2.w;
        }
        const float scale = 0.088388347648318447f;  // 128^-0.5
        Sm[i0][jc]          = s00 * scale;
        Sm[i0][jc + 32]     = s01 * scale;
        Sm[i0][jc + 64]     = s02 * scale;
        Sm[i0 + 1][jc]      = s10 * scale;
        Sm[i0 + 1][jc + 32] = s11 * scale;
        Sm[i0 + 1][jc + 64] = s12 * scale;
    }
    __syncthreads();

    for (int idx = tid; idx < 96 * 32; idx += 256) {
        const int n = idx >> 5, dv = idx & 31;
        const int g = (n < 16) ? (s * 16 + n) : (128 + s * 80 + (n - 16));
        *(float4*)&Buf[n][dv * 4] =
            *(const float4*)(KV + (size_t)g * 1536 + 768 + h * 128 + dv * 4);
    }
    {
        const int i = tid >> 4, l = tid & 15;
        const float v0 = Sm[i][l],      v1 = Sm[i][l + 16], v2 = Sm[i][l + 32],
                    v3 = Sm[i][l + 48], v4 = Sm[i][l + 64], v5 = Sm[i][l + 80];
        float m = fmaxf(fmaxf(fmaxf(v0, v1), fmaxf(v2, v3)), fmaxf(v4, v5));
        #pragma unroll
        for (int o = 8; o >= 1; o >>= 1) m = fmaxf(m, __shfl_xor(m, o, 16));
        const float e0 = __expf(v0 - m), e1 = __expf(v1 - m), e2 = __expf(v2 - m),
                    e3 = __expf(v3 - m), e4 = __expf(v4 - m), e5 = __expf(v5 - m);
        float sum = e0 + e1 + e2 + e3 + e4 + e5;
        #pragma unroll
        for (int o = 8; o >= 1; o >>= 1) sum += __shfl_xor(sum, o, 16);
        const float inv = 1.0f / sum;
        Sm[i][l]      = e0 * inv; Sm[i][l + 16] = e1 * inv; Sm[i][l + 32] = e2 * inv;
        Sm[i][l + 48] = e3 * inv; Sm[i][l + 64] = e4 * inv; Sm[i][l + 80] = e5 * inv;
    }
    __syncthreads();

    {
        const int i = tid >> 4, dv = tid & 15;
        float4 o0 = make_float4(0, 0, 0, 0), o1 = make_float4(0, 0, 0, 0);
        #pragma unroll 4
        for (int j = 0; j < 96; ++j) {
            const float p = Sm[i][j];
            const float4 va = *(const float4*)&Buf[j][dv * 4];
            const float4 vb = *(const float4*)&Buf[j][64 + dv * 4];
            o0.x += p * va.x; o0.y += p * va.y; o0.z += p * va.z; o0.w += p * va.w;
            o1.x += p * vb.x; o1.y += p * vb.y; o1.z += p * vb.z; o1.w += p * vb.w;
        }
        float* dst = AO + (size_t)(s * 16 + i) * 768 + h * 128;
        *(float4*)(dst + dv * 4)      = o0;
        *(float4*)(dst + 64 + dv * 4) = o1;
    }
}

// ---------------------------------------------------------------------------
// Kernel 3: fused per-scene epilogue. 8 blocks x 1024 threads (16 waves).
// AO->LDS; y1=relu(AO@Wout1) split-k; y2=y1@Wout2 || base=nodes@W1;
// LayerNorm+relu per row (wave shuffles); out=relu(h@W2 + nodes).
__global__ __launch_bounds__(1024) void k_epi(
    const float* __restrict__ AO, const float* __restrict__ agents,
    const float* __restrict__ Wout1, const float* __restrict__ Wout2,
    const float* __restrict__ W1, const float* __restrict__ ln_g,
    const float* __restrict__ ln_b, const float* __restrict__ W2,
    float* __restrict__ out)
{
    __shared__ float AOs[16 * 768];   // 48 KB
    __shared__ float nr[16][128];     // 8 KB
    __shared__ float y1[16][128];     // 8 KB
    __shared__ float ps[16][128];     // 8 KB (split-k reduce temp)
    __shared__ float tb[16][128];     // 8 KB (t = y2 + base)
    __shared__ float hb[16][128];     // 8 KB (post-LN relu)

    const int s = blockIdx.x;
    const int tid = threadIdx.x;

    // stage AO (16x768 contiguous) + agent rows
    {
        const float* src = AO + (size_t)s * 16 * 768;
        #pragma unroll
        for (int i = 0; i < 3; ++i) {
            const int t = tid + i * 1024;
            *(float4*)&AOs[t * 4] = *(const float4*)(src + t * 4);
        }
        if (tid < 512) {
            const int r = tid >> 5, c = tid & 31;
            *(float4*)&nr[r][c * 4] =
                *(const float4*)(agents + (size_t)(s * 16 + r) * 128 + c * 4);
        }
    }
    __syncthreads();

    const int c4 = tid & 31;          // f4 column
    const int r  = (tid >> 5) & 15;   // row (agent within scene)
    const int hi = tid >> 9;          // split-k half / role bit

    // ---- y1 = relu(AO @ Wout1), 2-way split-k over K=768
    {
        const int k0 = hi * 384;
        float4 acc = make_float4(0, 0, 0, 0);
        const float* wp = Wout1 + (size_t)k0 * 128 + c4 * 4;
        const float* ap = &AOs[r * 768 + k0];
        #pragma unroll 4
        for (int k = 0; k < 384; ++k) {
            const float a = ap[k];
            const float4 w = *(const float4*)(wp + (size_t)k * 128);
            acc.x += a * w.x; acc.y += a * w.y; acc.z += a * w.z; acc.w += a * w.w;
        }
        if (hi) *(float4*)&ps[r][c4 * 4] = acc;
        __syncthreads();
        if (!hi) {
            const float4 p = *(const float4*)&ps[r][c4 * 4];
            float4 v;
            v.x = fmaxf(acc.x + p.x, 0.f); v.y = fmaxf(acc.y + p.y, 0.f);
            v.z = fmaxf(acc.z + p.z, 0.f); v.w = fmaxf(acc.w + p.w, 0.f);
            *(float4*)&y1[r][c4 * 4] = v;
        }
        __syncthreads();
    }

    // ---- hi=0: y2 = y1 @ Wout2 ; hi=1: base = nodes_row @ W1
    {
        const float* Wm  = hi ? W1 : Wout2;
        const float* src = hi ? &nr[r][0] : &y1[r][0];
        float4 acc = make_float4(0, 0, 0, 0);
        const float* wp = Wm + c4 * 4;
        #pragma unroll 4
        for (int k = 0; k < 128; ++k) {
            const float a = src[k];
            const float4 w = *(const float4*)(wp + (size_t)k * 128);
            acc.x += a * w.x; acc.y += a * w.y; acc.z += a * w.z; acc.w += a * w.w;
        }
        if (hi) *(float4*)&ps[r][c4 * 4] = acc;
        __syncthreads();
        if (!hi) {
            const float4 p = *(const float4*)&ps[r][c4 * 4];
            float4 t;
            t.x = acc.x + p.x; t.y = acc.y + p.y;
            t.z = acc.z + p.z; t.w = acc.w + p.w;
            *(float4*)&tb[r][c4 * 4] = t;
        }
        __syncthreads();
    }

    // ---- LayerNorm + relu, wave w -> row w
    {
        const int w = tid >> 6, l = tid & 63;
        const float t0 = tb[w][l], t1 = tb[w][l + 64];
        float s1 = t0 + t1, s2 = t0 * t0 + t1 * t1;
        #pragma unroll
        for (int o = 32; o >= 1; o >>= 1) {
            s1 += __shfl_xor(s1, o);
            s2 += __shfl_xor(s2, o);
        }
        const float mu  = s1 * (1.0f / 128.0f);
        const float var = s2 * (1.0f / 128.0f) - mu * mu;
        const float ri  = rsqrtf(var + LN_EPS);
        hb[w][l]      = fmaxf((t0 - mu) * ri * ln_g[l]      + ln_b[l],      0.f);
        hb[w][l + 64] = fmaxf((t1 - mu) * ri * ln_g[l + 64] + ln_b[l + 64], 0.f);
    }
    __syncthreads();

    // ---- out = relu(hb @ W2 + nodes_row), 2-way split-k over K=128
    {
        const int k0 = hi * 64;
        float4 acc = make_float4(0, 0, 0, 0);
        const float* wp = W2 + (size_t)k0 * 128 + c4 * 4;
        const float* src = &hb[r][k0];
        #pragma unroll 8
        for (int k = 0; k < 64; ++k) {
            const float a = src[k];
            const float4 w = *(const float4*)(wp + (size_t)k * 128);
            acc.x += a * w.x; acc.y += a * w.y; acc.z += a * w.z; acc.w += a * w.w;
        }
        if (hi) *(float4*)&ps[r][c4 * 4] = acc;
        __syncthreads();
        if (!hi) {
            const float4 p = *(const float4*)&ps[r][c4 * 4];
            const float4 n = *(const float4*)&nr[r][c4 * 4];
            float4 o;
            o.x = fmaxf(acc.x + p.x + n.x, 0.f);
            o.y = fmaxf(acc.y + p.y + n.y, 0.f);
            o.z = fmaxf(acc.z + p.z + n.z, 0.f);
            o.w = fmaxf(acc.w + p.w + n.w, 0.f);
            *(float4*)(out + (size_t)(s * 16 + r) * 128 + c4 * 4) = o;
        }
    }
}

// ---------------------------------------------------------------------------
extern "C" void kernel_launch(void* const* d_in, const int* in_sizes, int n_in,
                              void* d_out, int out_size, void* d_ws, size_t ws_size,
                              hipStream_t stream)
{
    const float* agents = (const float*)d_in[0];
    const float* lanes  = (const float*)d_in[1];
    const float* Wq     = (const float*)d_in[2];
    const float* Wk     = (const float*)d_in[3];
    const float* Wv     = (const float*)d_in[4];
    const float* Wout1  = (const float*)d_in[5];
    const float* Wout2  = (const float*)d_in[6];
    const float* W1     = (const float*)d_in[7];
    const float* ln_g   = (const float*)d_in[8];
    const float* ln_b   = (const float*)d_in[9];
    const float* W2     = (const float*)d_in[10];
    // d_in[11], d_in[12] = hi, wi — static dense per-scene structure, unused.

    float* ws = (float*)d_ws;
    float* KV = ws;                     // [768][1536]
    float* Qb = KV + 768 * 1536;        // [128][768]
    float* AO = Qb + 128 * 768;         // [128][768]
    float* outp = (float*)d_out;

    k_qkv <<<312, 256, 0, stream>>>(agents, lanes, Wq, Wk, Wv, KV, Qb);
    k_attn<<<48, 256, 0, stream>>>(KV, Qb, AO);
    k_epi <<<8, 1024, 0, stream>>>(AO, agents, Wout1, Wout2, W1, ln_g, ln_b, W2, outp);
}

// Round 4
// 117.378 us; speedup vs baseline: 1.4676x; 1.4676x over previous
//
#include <hip/hip_runtime.h>
#include <math.h>

#define LN_EPS 1e-5f

// Problem: B=8 scenes, A=16 agents, L=80 lanes, D=128, H=6.
// N=768 nodes (128 agents first), 96 nodes/scene, dense per-scene attention.
// Key identity: S = (src@Wq_h)(dst@Wk_h)^T = src @ (Wq_h Wk_h^T) @ dst^T,
// so we precompute M_h = Wq_h Wk_h^T and never materialize K (or Q).
// ws layout (floats): M[6][128][128] | base[128][128] | AO[128][768] | y1p[6][128][128]

// ---------------------------------------------------------------------------
// Kernel 0: k_prep — 28 blocks x 256 threads.
//   blocks 0..23 : M_h = Wq_h^T-product: M[h][i][j] = sum_k Wq[k][h128+i]*Wk[k][h128+j]
//   blocks 24..27: base = agents @ W1   (needed only by k_f2)
// Single full-K LDS stage (deep load pipeline), 4x4 per thread.
__global__ __launch_bounds__(256) void k_prep(
    const float* __restrict__ Wq, const float* __restrict__ Wk,
    const float* __restrict__ agents, const float* __restrict__ W1,
    float* __restrict__ M, float* __restrict__ base)
{
    __shared__ float As[128][68];   // [k][i] 34 KB
    __shared__ float Bs[128][68];   // [k][j] 34 KB

    const int tid = threadIdx.x;
    const int bid = blockIdx.x;

    float* dst;
    if (bid < 24) {
        const int h = bid >> 2, quad = bid & 3;
        const int i0 = (quad >> 1) * 64, j0 = (quad & 1) * 64;
        // both operands row-major in k: coalesced f4 loads
        const int c4 = tid & 15, kr = tid >> 4;
        #pragma unroll
        for (int ii = 0; ii < 8; ++ii) {
            const int k = kr + 16 * ii;
            *(float4*)&As[k][c4 * 4] =
                *(const float4*)(Wq + (size_t)k * 768 + h * 128 + i0 + c4 * 4);
            *(float4*)&Bs[k][c4 * 4] =
                *(const float4*)(Wk + (size_t)k * 768 + h * 128 + j0 + c4 * 4);
        }
        dst = M + (size_t)h * 16384 + (size_t)i0 * 128 + j0;
    } else {
        const int quad = bid - 24;
        const int i0 = (quad >> 1) * 64, j0 = (quad & 1) * 64;
        // A = agents rows, transposed into As[k][row]
        const int row = tid >> 2, kq = tid & 3;
        #pragma unroll
        for (int j = 0; j < 8; ++j) {
            const int k0 = kq * 4 + j * 16;
            const float4 a = *(const float4*)(agents + (size_t)(i0 + row) * 128 + k0);
            As[k0 + 0][row] = a.x; As[k0 + 1][row] = a.y;
            As[k0 + 2][row] = a.z; As[k0 + 3][row] = a.w;
        }
        const int c4 = tid & 15, kr = tid >> 4;
        #pragma unroll
        for (int ii = 0; ii < 8; ++ii) {
            const int k = kr + 16 * ii;
            *(float4*)&Bs[k][c4 * 4] =
                *(const float4*)(W1 + (size_t)k * 128 + j0 + c4 * 4);
        }
        dst = base + (size_t)i0 * 128 + j0;
    }
    __syncthreads();

    const int tx = tid & 15, ty = tid >> 4;
    float acc[4][4] = {};
    #pragma unroll 8
    for (int k = 0; k < 128; ++k) {
        const float4 a = *(const float4*)&As[k][ty * 4];
        const float4 b = *(const float4*)&Bs[k][tx * 4];
        const float av[4] = {a.x, a.y, a.z, a.w};
        #pragma unroll
        for (int i = 0; i < 4; ++i) {
            acc[i][0] += av[i] * b.x; acc[i][1] += av[i] * b.y;
            acc[i][2] += av[i] * b.z; acc[i][3] += av[i] * b.w;
        }
    }
    #pragma unroll
    for (int i = 0; i < 4; ++i)
        *(float4*)(dst + (size_t)(ty * 4 + i) * 128 + tx * 4) =
            make_float4(acc[i][0], acc[i][1], acc[i][2], acc[i][3]);
}

// ---------------------------------------------------------------------------
// Kernel 1: fused attention. 96 blocks = (scene, head, half) x 512 threads.
// LDS: nodes (raw), V-half; T = agents@M_h; S = T@nodes^T; half-wave softmax; PV.
__global__ __launch_bounds__(512) void k_attn_f(
    const float* __restrict__ agents, const float* __restrict__ lanes,
    const float* __restrict__ Wv, const float* __restrict__ M,
    float* __restrict__ AO)
{
    __shared__ float Ns[96][132];   // raw nodes of scene    50.7 KB
    __shared__ float Vh[96][68];    // V half (64 cols)      26.1 KB
    __shared__ float Tt[16][132];   // T = agents@M_h         8.4 KB
    __shared__ float Sm[16][100];   // P (post-softmax)       6.4 KB

    const int tid = threadIdx.x;
    const int b = blockIdx.x;
    const int s = b / 12, r12 = b % 12;
    const int h = r12 >> 1, half = r12 & 1;

    // ---- load raw nodes of scene s
    for (int idx = tid; idx < 96 * 32; idx += 512) {
        const int n = idx >> 5, c4 = idx & 31;
        const float* src = (n < 16) ? (agents + (size_t)(s * 16 + n) * 128)
                                    : (lanes + (size_t)(s * 80 + n - 16) * 128);
        *(float4*)&Ns[n][c4 * 4] = *(const float4*)(src + c4 * 4);
    }
    __syncthreads();

    // ---- V half = relu(nodes @ Wv_h[:, half]) : rows {rg, rg+32, rg+64}, 1 f4 col
    {
        const int c4 = tid & 15, rg = tid >> 4;   // rg 0..31
        const float* wp = Wv + h * 128 + half * 64 + c4 * 4;
        float4 a0 = make_float4(0,0,0,0), a1 = a0, a2 = a0;
        #pragma unroll 8
        for (int k = 0; k < 128; ++k) {
            const float4 w = *(const float4*)(wp + (size_t)k * 768);
            const float n0 = Ns[rg][k], n1 = Ns[rg + 32][k], n2 = Ns[rg + 64][k];
            a0.x += n0 * w.x; a0.y += n0 * w.y; a0.z += n0 * w.z; a0.w += n0 * w.w;
            a1.x += n1 * w.x; a1.y += n1 * w.y; a1.z += n1 * w.z; a1.w += n1 * w.w;
            a2.x += n2 * w.x; a2.y += n2 * w.y; a2.z += n2 * w.z; a2.w += n2 * w.w;
        }
        a0.x = fmaxf(a0.x, 0.f); a0.y = fmaxf(a0.y, 0.f);
        a0.z = fmaxf(a0.z, 0.f); a0.w = fmaxf(a0.w, 0.f);
        a1.x = fmaxf(a1.x, 0.f); a1.y = fmaxf(a1.y, 0.f);
        a1.z = fmaxf(a1.z, 0.f); a1.w = fmaxf(a1.w, 0.f);
        a2.x = fmaxf(a2.x, 0.f); a2.y = fmaxf(a2.y, 0.f);
        a2.z = fmaxf(a2.z, 0.f); a2.w = fmaxf(a2.w, 0.f);
        *(float4*)&Vh[rg][c4 * 4]      = a0;
        *(float4*)&Vh[rg + 32][c4 * 4] = a1;
        *(float4*)&Vh[rg + 64][c4 * 4] = a2;
    }

    // ---- T = agents_s @ M_h : row r (=agent), 1 f4 col per thread
    {
        const int c4 = tid & 31, r = tid >> 5;
        const float* mp = M + (size_t)h * 16384 + c4 * 4;
        float4 acc = make_float4(0,0,0,0);
        #pragma unroll 8
        for (int k = 0; k < 128; ++k) {
            const float4 m4 = *(const float4*)(mp + (size_t)k * 128);
            const float a = Ns[r][k];
            acc.x += a * m4.x; acc.y += a * m4.y;
            acc.z += a * m4.z; acc.w += a * m4.w;
        }
        *(float4*)&Tt[r][c4 * 4] = acc;
    }
    __syncthreads();

    // ---- S row i = T[i] . nodes[j], j in {jc, jc+32, jc+64}; softmax within
    //      the 32-lane group that owns row i (no barrier needed afterwards:
    //      PV for row i runs on the same 32 lanes).
    {
        const int i = tid >> 5, jc = tid & 31;
        float s0 = 0, s1 = 0, s2 = 0;
        #pragma unroll 4
        for (int kk = 0; kk < 32; ++kk) {
            const float4 t4 = *(const float4*)&Tt[i][kk * 4];
            const float4 a  = *(const float4*)&Ns[jc][kk * 4];
            const float4 bb = *(const float4*)&Ns[jc + 32][kk * 4];
            const float4 c  = *(const float4*)&Ns[jc + 64][kk * 4];
            s0 += t4.x*a.x  + t4.y*a.y  + t4.z*a.z  + t4.w*a.w;
            s1 += t4.x*bb.x + t4.y*bb.y + t4.z*bb.z + t4.w*bb.w;
            s2 += t4.x*c.x  + t4.y*c.y  + t4.z*c.z  + t4.w*c.w;
        }
        const float scale = 0.088388347648318447f;   // 128^-0.5
        s0 *= scale; s1 *= scale; s2 *= scale;
        float m = fmaxf(fmaxf(s0, s1), s2);
        #pragma unroll
        for (int o = 16; o >= 1; o >>= 1) m = fmaxf(m, __shfl_xor(m, o, 32));
        const float e0 = __expf(s0 - m), e1 = __expf(s1 - m), e2 = __expf(s2 - m);
        float sum = e0 + e1 + e2;
        #pragma unroll
        for (int o = 16; o >= 1; o >>= 1) sum += __shfl_xor(sum, o, 32);
        const float inv = 1.0f / sum;
        Sm[i][jc]      = e0 * inv;
        Sm[i][jc + 32] = e1 * inv;
        Sm[i][jc + 64] = e2 * inv;
    }

    // ---- O_half = P @ V_half : row i, 2 cols per thread
    {
        const int i = tid >> 5, d2 = tid & 31;
        float o0 = 0, o1 = 0;
        #pragma unroll 4
        for (int j = 0; j < 96; ++j) {
            const float p = Sm[i][j];
            const float2 v = *(const float2*)&Vh[j][2 * d2];
            o0 += p * v.x; o1 += p * v.y;
        }
        float* dst = AO + (size_t)(s * 16 + i) * 768 + h * 128 + half * 64 + 2 * d2;
        *(float2*)dst = make_float2(o0, o1);
    }
}

// ---------------------------------------------------------------------------
// Kernel 2: y1 partial slices (no atomics, no zero-init needed).
// 24 blocks = 6 K-slices x 4 (2x2 of 64x64). y1p[s6] = AO[:, s6*128:+128] @ Wout1-slice.
__global__ __launch_bounds__(256) void k_f1(
    const float* __restrict__ AO, const float* __restrict__ Wout1,
    float* __restrict__ y1p)
{
    __shared__ float As[128][68];
    __shared__ float Bs[128][68];

    const int tid = threadIdx.x;
    const int b = blockIdx.x;
    const int s6 = b >> 2, quad = b & 3;
    const int m0 = (quad >> 1) * 64, n0 = (quad & 1) * 64;

    {   // A transposed: As[k][m] = AO[m0+row][s6*128 + k]
        const int row = tid >> 2, kq = tid & 3;
        #pragma unroll
        for (int j = 0; j < 8; ++j) {
            const int k0 = kq * 4 + j * 16;
            const float4 a =
                *(const float4*)(AO + (size_t)(m0 + row) * 768 + s6 * 128 + k0);
            As[k0 + 0][row] = a.x; As[k0 + 1][row] = a.y;
            As[k0 + 2][row] = a.z; As[k0 + 3][row] = a.w;
        }
    }
    {   // B direct: Bs[k][n] = Wout1[s6*128+k][n0+n]
        const int c4 = tid & 15, kr = tid >> 4;
        #pragma unroll
        for (int ii = 0; ii < 8; ++ii) {
            const int k = kr + 16 * ii;
            *(float4*)&Bs[k][c4 * 4] =
                *(const float4*)(Wout1 + (size_t)(s6 * 128 + k) * 128 + n0 + c4 * 4);
        }
    }
    __syncthreads();

    const int tx = tid & 15, ty = tid >> 4;
    float acc[4][4] = {};
    #pragma unroll 8
    for (int k = 0; k < 128; ++k) {
        const float4 a = *(const float4*)&As[k][ty * 4];
        const float4 bv = *(const float4*)&Bs[k][tx * 4];
        const float av[4] = {a.x, a.y, a.z, a.w};
        #pragma unroll
        for (int i = 0; i < 4; ++i) {
            acc[i][0] += av[i] * bv.x; acc[i][1] += av[i] * bv.y;
            acc[i][2] += av[i] * bv.z; acc[i][3] += av[i] * bv.w;
        }
    }
    float* dst = y1p + (size_t)s6 * 16384 + (size_t)m0 * 128 + n0;
    #pragma unroll
    for (int i = 0; i < 4; ++i)
        *(float4*)(dst + (size_t)(ty * 4 + i) * 128 + tx * 4) =
            make_float4(acc[i][0], acc[i][1], acc[i][2], acc[i][3]);
}

// ---------------------------------------------------------------------------
// Kernel 3: per-agent tail. 128 blocks x 512 threads (R2's proven shape).
// y1 = relu(sum slices); y2 = y1@Wout2 (4-way split-k); t = y2+base; LN+relu;
// out = relu(h@W2 + agents).
__global__ __launch_bounds__(512) void k_f2(
    const float* __restrict__ y1p, const float* __restrict__ base,
    const float* __restrict__ agents, const float* __restrict__ Wout2,
    const float* __restrict__ ln_g, const float* __restrict__ ln_b,
    const float* __restrict__ W2, float* __restrict__ out)
{
    const int a = blockIdx.x;
    const int tid = threadIdx.x;
    __shared__ float y1s[128];
    __shared__ float nr[128];
    __shared__ float br[128];
    __shared__ float hb[128];
    __shared__ float ps[512];
    __shared__ float red[4];

    if (tid < 32) {
        float4 acc = make_float4(0,0,0,0);
        #pragma unroll
        for (int s6 = 0; s6 < 6; ++s6) {
            const float4 v =
                *(const float4*)(y1p + (size_t)s6 * 16384 + (size_t)a * 128 + tid * 4);
            acc.x += v.x; acc.y += v.y; acc.z += v.z; acc.w += v.w;
        }
        y1s[tid * 4 + 0] = fmaxf(acc.x, 0.f); y1s[tid * 4 + 1] = fmaxf(acc.y, 0.f);
        y1s[tid * 4 + 2] = fmaxf(acc.z, 0.f); y1s[tid * 4 + 3] = fmaxf(acc.w, 0.f);
    } else if (tid < 64) {
        const int t = tid - 32;
        *(float4*)&nr[t * 4] = *(const float4*)(agents + (size_t)a * 128 + t * 4);
    } else if (tid < 96) {
        const int t = tid - 64;
        *(float4*)&br[t * 4] = *(const float4*)(base + (size_t)a * 128 + t * 4);
    }
    __syncthreads();

    const int d = tid & 127, g = tid >> 7;   // 4-way split-k (K=32 each)
    {
        const int k0 = g * 32;
        float p = 0.f;
        #pragma unroll 8
        for (int k = 0; k < 32; ++k)
            p += y1s[k0 + k] * Wout2[(size_t)(k0 + k) * 128 + d];
        ps[tid] = p;
    }
    __syncthreads();

    float tval = 0.f;
    if (tid < 128) tval = ps[d] + ps[128 + d] + ps[256 + d] + ps[384 + d] + br[d];
    float s1 = tval, s2 = tval * tval;
    #pragma unroll
    for (int o = 32; o >= 1; o >>= 1) { s1 += __shfl_xor(s1, o); s2 += __shfl_xor(s2, o); }
    if (tid < 128 && (tid & 63) == 0) {
        red[(tid >> 6) * 2] = s1; red[(tid >> 6) * 2 + 1] = s2;
    }
    __syncthreads();
    if (tid < 128) {
        const float S1 = red[0] + red[2], S2 = red[1] + red[3];
        const float mu  = S1 * (1.0f / 128.0f);
        const float var = S2 * (1.0f / 128.0f) - mu * mu;
        const float rin = rsqrtf(var + LN_EPS);
        hb[tid] = fmaxf((tval - mu) * rin * ln_g[tid] + ln_b[tid], 0.0f);
    }
    __syncthreads();

    {
        const int k0 = g * 32;
        float p = 0.f;
        #pragma unroll 8
        for (int k = 0; k < 32; ++k)
            p += hb[k0 + k] * W2[(size_t)(k0 + k) * 128 + d];
        ps[tid] = p;
    }
    __syncthreads();
    if (tid < 128)
        out[(size_t)a * 128 + d] =
            fmaxf(ps[d] + ps[128 + d] + ps[256 + d] + ps[384 + d] + nr[d], 0.0f);
}

// ---------------------------------------------------------------------------
extern "C" void kernel_launch(void* const* d_in, const int* in_sizes, int n_in,
                              void* d_out, int out_size, void* d_ws, size_t ws_size,
                              hipStream_t stream)
{
    const float* agents = (const float*)d_in[0];
    const float* lanes  = (const float*)d_in[1];
    const float* Wq     = (const float*)d_in[2];
    const float* Wk     = (const float*)d_in[3];
    const float* Wv     = (const float*)d_in[4];
    const float* Wout1  = (const float*)d_in[5];
    const float* Wout2  = (const float*)d_in[6];
    const float* W1     = (const float*)d_in[7];
    const float* ln_g   = (const float*)d_in[8];
    const float* ln_b   = (const float*)d_in[9];
    const float* W2     = (const float*)d_in[10];
    // d_in[11], d_in[12] = hi, wi — static dense per-scene structure, unused.

    float* ws = (float*)d_ws;
    float* M    = ws;                 // [6][128][128]
    float* base = M + 6 * 16384;      // [128][128]
    float* AO   = base + 16384;       // [128][768]
    float* y1p  = AO + 128 * 768;     // [6][128][128]
    float* outp = (float*)d_out;

    k_prep  <<<28, 256, 0, stream>>>(Wq, Wk, agents, W1, M, base);
    k_attn_f<<<96, 512, 0, stream>>>(agents, lanes, Wv, M, AO);
    k_f1    <<<24, 256, 0, stream>>>(AO, Wout1, y1p);
    k_f2    <<<128, 512, 0, stream>>>(y1p, base, agents, Wout2, ln_g, ln_b, W2, outp);
}

// Round 5
// 107.868 us; speedup vs baseline: 1.5970x; 1.0882x over previous
//
#include <hip/hip_runtime.h>
#include <math.h>

#define LN_EPS 1e-5f

// Problem: B=8 scenes, A=16 agents, L=80 lanes, D=128, H=6.
// N=768 nodes (128 agents first), 96 nodes/scene, dense per-scene attention.
// S = (src@Wq_h)(dst@Wk_h)^T computed as T = Q@Wk_h^T (per block), S = T@nodes^T
// -> K is never materialized. V/Q/base are precomputed by one wide GEMM kernel.
// ws floats: V[768][768] | Qb[128][768] | base[128][128] | AO[128][768] | y1p[12][128][128]

// ---------------------------------------------------------------------------
// Kernel A: 64x64 tiles, full LDS staging (no mid-loop global loads).
//   blocks 0..143 : V = relu(nodes @ Wv)   (12 rb x 12 cb)
//   blocks 144..167: Qb = agents @ Wq      (2 rb x 12 cb)
//   blocks 168..171: base = agents @ W1    (2 rb x 2 cb)
__global__ __launch_bounds__(256) void k_qv(
    const float* __restrict__ agents, const float* __restrict__ lanes,
    const float* __restrict__ Wv, const float* __restrict__ Wq,
    const float* __restrict__ W1, float* __restrict__ V,
    float* __restrict__ Qb, float* __restrict__ base)
{
    __shared__ float As[128][68];   // [k][row] 34.8 KB
    __shared__ float Bs[128][68];   // [k][col] 34.8 KB

    const int tid = threadIdx.x;
    const int bid = blockIdx.x;

    const float* W;
    float* Out;
    int r0, wc0, wstride, dstride;
    bool dorelu = false;
    if (bid < 144) {
        const int br = bid % 12, bc = bid / 12;
        r0 = br * 64; W = Wv; wc0 = bc * 64; wstride = 768;
        Out = V; dstride = 768; dorelu = true;
    } else if (bid < 168) {
        const int idx = bid - 144;
        r0 = (idx & 1) * 64; W = Wq; wc0 = (idx >> 1) * 64; wstride = 768;
        Out = Qb; dstride = 768;
    } else {
        const int idx = bid - 168;
        r0 = (idx & 1) * 64; W = W1; wc0 = (idx >> 1) * 64; wstride = 128;
        Out = base; dstride = 128;
    }

    // stage A (64 rows x 128 k) transposed
    {
        const int row = tid >> 2, kv = tid & 3;
        const int gr = r0 + row;
        const float* src = (gr < 128) ? (agents + (size_t)gr * 128)
                                      : (lanes + (size_t)(gr - 128) * 128);
        #pragma unroll
        for (int j = 0; j < 8; ++j) {
            const int k0 = kv * 4 + j * 16;
            const float4 a = *(const float4*)(src + k0);
            As[k0 + 0][row] = a.x; As[k0 + 1][row] = a.y;
            As[k0 + 2][row] = a.z; As[k0 + 3][row] = a.w;
        }
    }
    // stage B (128 k x 64 cols) direct, coalesced
    {
        const int kr = tid >> 4, c4 = tid & 15;
        #pragma unroll
        for (int i = 0; i < 8; ++i) {
            const int k = kr + 16 * i;
            *(float4*)&Bs[k][c4 * 4] =
                *(const float4*)(W + (size_t)k * wstride + wc0 + c4 * 4);
        }
    }
    __syncthreads();

    const int tx = tid & 15, ty = tid >> 4;
    float acc[4][4] = {};
    #pragma unroll 8
    for (int k = 0; k < 128; ++k) {
        const float4 a = *(const float4*)&As[k][ty * 4];
        const float4 b = *(const float4*)&Bs[k][tx * 4];
        const float av[4] = {a.x, a.y, a.z, a.w};
        #pragma unroll
        for (int i = 0; i < 4; ++i) {
            acc[i][0] += av[i] * b.x; acc[i][1] += av[i] * b.y;
            acc[i][2] += av[i] * b.z; acc[i][3] += av[i] * b.w;
        }
    }
    #pragma unroll
    for (int i = 0; i < 4; ++i) {
        float4 v = make_float4(acc[i][0], acc[i][1], acc[i][2], acc[i][3]);
        if (dorelu) {
            v.x = fmaxf(v.x, 0.f); v.y = fmaxf(v.y, 0.f);
            v.z = fmaxf(v.z, 0.f); v.w = fmaxf(v.w, 0.f);
        }
        *(float4*)(Out + (size_t)(r0 + ty * 4 + i) * dstride + wc0 + tx * 4) = v;
    }
}

// ---------------------------------------------------------------------------
// Kernel B: attention. 96 blocks = (scene, head, half) x 512 threads.
// All operands burst-staged in LDS; T from 32-row Wk chunks; half-wave softmax.
__global__ __launch_bounds__(512) void k_attn2(
    const float* __restrict__ agents, const float* __restrict__ lanes,
    const float* __restrict__ Wk, const float* __restrict__ V,
    const float* __restrict__ Qb, float* __restrict__ AO)
{
    __shared__ float Ns[96][132];   // raw nodes         50.7 KB
    __shared__ float Vh[96][68];    // V half (64 cols)  26.1 KB
    __shared__ float Qs[16][132];   // Q rows             8.5 KB
    __shared__ float Tt[16][132];   // T = Q@Wk_h^T       8.5 KB
    __shared__ float Sm[16][100];   // P                  6.4 KB
    __shared__ float Wc[32][132];   // Wk chunk          16.9 KB

    const int tid = threadIdx.x;
    const int b = blockIdx.x;
    const int s = b / 12, r12 = b % 12;
    const int h = r12 >> 1, half = r12 & 1;

    // ---- burst loads: nodes, V-half, Q rows
    #pragma unroll
    for (int ii = 0; ii < 6; ++ii) {
        const int idx = tid + ii * 512;          // 96 x 32 f4
        const int n = idx >> 5, c4 = idx & 31;
        const float* src = (n < 16) ? (agents + (size_t)(s * 16 + n) * 128)
                                    : (lanes + (size_t)(s * 80 + n - 16) * 128);
        *(float4*)&Ns[n][c4 * 4] = *(const float4*)(src + c4 * 4);
    }
    #pragma unroll
    for (int ii = 0; ii < 3; ++ii) {
        const int idx = tid + ii * 512;          // 96 x 16 f4
        const int n = idx >> 4, c4 = idx & 15;
        const int g = (n < 16) ? (s * 16 + n) : (128 + s * 80 + (n - 16));
        *(float4*)&Vh[n][c4 * 4] =
            *(const float4*)(V + (size_t)g * 768 + h * 128 + half * 64 + c4 * 4);
    }
    {
        const int r = tid >> 5, c4 = tid & 31;   // 16 x 32 f4
        *(float4*)&Qs[r][c4 * 4] =
            *(const float4*)(Qb + (size_t)(s * 16 + r) * 768 + h * 128 + c4 * 4);
    }
    __syncthreads();

    // ---- T[r][k] = sum_c Q[r][c] * Wk[k][h*128+c], 4 chunks of 32 k-rows
    const int r = tid >> 5, kc = tid & 31;
    for (int ck = 0; ck < 4; ++ck) {
        {   // cooperative chunk load: 32 rows x 32 f4
            const int i0 = tid * 2;
            #pragma unroll
            for (int ii = 0; ii < 2; ++ii) {
                const int idx = i0 + ii;
                const int row = idx >> 5, c4 = idx & 31;
                *(float4*)&Wc[row][c4 * 4] =
                    *(const float4*)(Wk + (size_t)(ck * 32 + row) * 768 +
                                     h * 128 + c4 * 4);
            }
        }
        __syncthreads();
        {
            float acc = 0.f;
            #pragma unroll 8
            for (int c4 = 0; c4 < 32; ++c4) {
                const float4 q = *(const float4*)&Qs[r][c4 * 4];
                const float4 w = *(const float4*)&Wc[kc][c4 * 4];
                acc += q.x * w.x + q.y * w.y + q.z * w.z + q.w * w.w;
            }
            Tt[r][ck * 32 + kc] = acc;
        }
        __syncthreads();
    }

    // ---- S row i over j in {jc, jc+32, jc+64}; softmax in the owning half-wave
    {
        const int i = r, jc = kc;
        float s0 = 0, s1 = 0, s2 = 0;
        #pragma unroll 4
        for (int kk = 0; kk < 32; ++kk) {
            const float4 t4 = *(const float4*)&Tt[i][kk * 4];
            const float4 a  = *(const float4*)&Ns[jc][kk * 4];
            const float4 bb = *(const float4*)&Ns[jc + 32][kk * 4];
            const float4 c  = *(const float4*)&Ns[jc + 64][kk * 4];
            s0 += t4.x*a.x  + t4.y*a.y  + t4.z*a.z  + t4.w*a.w;
            s1 += t4.x*bb.x + t4.y*bb.y + t4.z*bb.z + t4.w*bb.w;
            s2 += t4.x*c.x  + t4.y*c.y  + t4.z*c.z  + t4.w*c.w;
        }
        const float scale = 0.088388347648318447f;   // 128^-0.5
        s0 *= scale; s1 *= scale; s2 *= scale;
        float m = fmaxf(fmaxf(s0, s1), s2);
        #pragma unroll
        for (int o = 16; o >= 1; o >>= 1) m = fmaxf(m, __shfl_xor(m, o, 32));
        const float e0 = __expf(s0 - m), e1 = __expf(s1 - m), e2 = __expf(s2 - m);
        float sum = e0 + e1 + e2;
        #pragma unroll
        for (int o = 16; o >= 1; o >>= 1) sum += __shfl_xor(sum, o, 32);
        const float inv = 1.0f / sum;
        Sm[i][jc]      = e0 * inv;
        Sm[i][jc + 32] = e1 * inv;
        Sm[i][jc + 64] = e2 * inv;
    }

    // ---- O_half = P @ V_half (row i owned by same half-wave; Vh ready)
    {
        const int i = r, d = kc;       // 2 cols per thread
        float o0 = 0, o1 = 0;
        #pragma unroll 4
        for (int j = 0; j < 96; ++j) {
            const float p = Sm[i][j];
            const float2 v = *(const float2*)&Vh[j][2 * d];
            o0 += p * v.x; o1 += p * v.y;
        }
        float* dst = AO + (size_t)(s * 16 + i) * 768 + h * 128 + half * 64 + 2 * d;
        *(float2*)dst = make_float2(o0, o1);
    }
}

// ---------------------------------------------------------------------------
// Kernel C: y1 partial slices. 48 blocks = 12 K-slices(64) x 4 quads (64x64).
__global__ __launch_bounds__(256) void k_f1w(
    const float* __restrict__ AO, const float* __restrict__ Wout1,
    float* __restrict__ y1p)
{
    __shared__ float As[64][68];
    __shared__ float Bs[64][68];

    const int tid = threadIdx.x;
    const int b = blockIdx.x;
    const int ks = b >> 2, quad = b & 3;
    const int m0 = (quad >> 1) * 64, n0 = (quad & 1) * 64;

    {   // A transposed: As[k][m] = AO[m0+row][ks*64 + k]
        const int row = tid >> 2, kq = tid & 3;
        #pragma unroll
        for (int j = 0; j < 4; ++j) {
            const int k0 = kq * 4 + j * 16;
            const float4 a =
                *(const float4*)(AO + (size_t)(m0 + row) * 768 + ks * 64 + k0);
            As[k0 + 0][row] = a.x; As[k0 + 1][row] = a.y;
            As[k0 + 2][row] = a.z; As[k0 + 3][row] = a.w;
        }
    }
    {   // B: Bs[k][n] = Wout1[ks*64+k][n0+n]
        const int kr = tid >> 4, c4 = tid & 15;
        #pragma unroll
        for (int i = 0; i < 4; ++i) {
            const int k = kr + 16 * i;
            *(float4*)&Bs[k][c4 * 4] =
                *(const float4*)(Wout1 + (size_t)(ks * 64 + k) * 128 + n0 + c4 * 4);
        }
    }
    __syncthreads();

    const int tx = tid & 15, ty = tid >> 4;
    float acc[4][4] = {};
    #pragma unroll 8
    for (int k = 0; k < 64; ++k) {
        const float4 a = *(const float4*)&As[k][ty * 4];
        const float4 bv = *(const float4*)&Bs[k][tx * 4];
        const float av[4] = {a.x, a.y, a.z, a.w};
        #pragma unroll
        for (int i = 0; i < 4; ++i) {
            acc[i][0] += av[i] * bv.x; acc[i][1] += av[i] * bv.y;
            acc[i][2] += av[i] * bv.z; acc[i][3] += av[i] * bv.w;
        }
    }
    float* dst = y1p + (size_t)ks * 16384 + (size_t)m0 * 128 + n0;
    #pragma unroll
    for (int i = 0; i < 4; ++i)
        *(float4*)(dst + (size_t)(ty * 4 + i) * 128 + tx * 4) =
            make_float4(acc[i][0], acc[i][1], acc[i][2], acc[i][3]);
}

// ---------------------------------------------------------------------------
// Kernel D: per-agent tail. 128 blocks x 512 threads (R2/R4 proven shape).
__global__ __launch_bounds__(512) void k_f2(
    const float* __restrict__ y1p, const float* __restrict__ base,
    const float* __restrict__ agents, const float* __restrict__ Wout2,
    const float* __restrict__ ln_g, const float* __restrict__ ln_b,
    const float* __restrict__ W2, float* __restrict__ out)
{
    const int a = blockIdx.x;
    const int tid = threadIdx.x;
    __shared__ float y1s[128];
    __shared__ float nr[128];
    __shared__ float br[128];
    __shared__ float hb[128];
    __shared__ float ps[512];
    __shared__ float red[4];

    if (tid < 32) {
        float4 acc = make_float4(0,0,0,0);
        #pragma unroll
        for (int ks = 0; ks < 12; ++ks) {
            const float4 v =
                *(const float4*)(y1p + (size_t)ks * 16384 + (size_t)a * 128 + tid * 4);
            acc.x += v.x; acc.y += v.y; acc.z += v.z; acc.w += v.w;
        }
        y1s[tid * 4 + 0] = fmaxf(acc.x, 0.f); y1s[tid * 4 + 1] = fmaxf(acc.y, 0.f);
        y1s[tid * 4 + 2] = fmaxf(acc.z, 0.f); y1s[tid * 4 + 3] = fmaxf(acc.w, 0.f);
    } else if (tid < 64) {
        const int t = tid - 32;
        *(float4*)&nr[t * 4] = *(const float4*)(agents + (size_t)a * 128 + t * 4);
    } else if (tid < 96) {
        const int t = tid - 64;
        *(float4*)&br[t * 4] = *(const float4*)(base + (size_t)a * 128 + t * 4);
    }
    __syncthreads();

    const int d = tid & 127, g = tid >> 7;   // 4-way split-k
    {
        const int k0 = g * 32;
        float p = 0.f;
        #pragma unroll 8
        for (int k = 0; k < 32; ++k)
            p += y1s[k0 + k] * Wout2[(size_t)(k0 + k) * 128 + d];
        ps[tid] = p;
    }
    __syncthreads();

    float tval = 0.f;
    if (tid < 128) tval = ps[d] + ps[128 + d] + ps[256 + d] + ps[384 + d] + br[d];
    float s1 = tval, s2 = tval * tval;
    #pragma unroll
    for (int o = 32; o >= 1; o >>= 1) { s1 += __shfl_xor(s1, o); s2 += __shfl_xor(s2, o); }
    if (tid < 128 && (tid & 63) == 0) {
        red[(tid >> 6) * 2] = s1; red[(tid >> 6) * 2 + 1] = s2;
    }
    __syncthreads();
    if (tid < 128) {
        const float S1 = red[0] + red[2], S2 = red[1] + red[3];
        const float mu  = S1 * (1.0f / 128.0f);
        const float var = S2 * (1.0f / 128.0f) - mu * mu;
        const float rin = rsqrtf(var + LN_EPS);
        hb[tid] = fmaxf((tval - mu) * rin * ln_g[tid] + ln_b[tid], 0.0f);
    }
    __syncthreads();

    {
        const int k0 = g * 32;
        float p = 0.f;
        #pragma unroll 8
        for (int k = 0; k < 32; ++k)
            p += hb[k0 + k] * W2[(size_t)(k0 + k) * 128 + d];
        ps[tid] = p;
    }
    __syncthreads();
    if (tid < 128)
        out[(size_t)a * 128 + d] =
            fmaxf(ps[d] + ps[128 + d] + ps[256 + d] + ps[384 + d] + nr[d], 0.0f);
}

// ---------------------------------------------------------------------------
extern "C" void kernel_launch(void* const* d_in, const int* in_sizes, int n_in,
                              void* d_out, int out_size, void* d_ws, size_t ws_size,
                              hipStream_t stream)
{
    const float* agents = (const float*)d_in[0];
    const float* lanes  = (const float*)d_in[1];
    const float* Wq     = (const float*)d_in[2];
    const float* Wk     = (const float*)d_in[3];
    const float* Wv     = (const float*)d_in[4];
    const float* Wout1  = (const float*)d_in[5];
    const float* Wout2  = (const float*)d_in[6];
    const float* W1     = (const float*)d_in[7];
    const float* ln_g   = (const float*)d_in[8];
    const float* ln_b   = (const float*)d_in[9];
    const float* W2     = (const float*)d_in[10];
    // d_in[11], d_in[12] = hi, wi — static dense per-scene structure, unused.

    float* ws = (float*)d_ws;
    float* V    = ws;                   // [768][768]
    float* Qb   = V + 768 * 768;        // [128][768]
    float* base = Qb + 128 * 768;       // [128][128]
    float* AO   = base + 16384;         // [128][768]
    float* y1p  = AO + 128 * 768;       // [12][128][128]
    float* outp = (float*)d_out;

    k_qv   <<<172, 256, 0, stream>>>(agents, lanes, Wv, Wq, W1, V, Qb, base);
    k_attn2<<<96, 512, 0, stream>>>(agents, lanes, Wk, V, Qb, AO);
    k_f1w  <<<48, 256, 0, stream>>>(AO, Wout1, y1p);
    k_f2   <<<128, 512, 0, stream>>>(y1p, base, agents, Wout2, ln_g, ln_b, W2, outp);
}